// Round 1
// 58.364 us; speedup vs baseline: 1.0627x; 1.0627x over previous
//
#include <hip/hip_runtime.h>

#define T 4096
#define B 8
#define WAVES 8
#define THREADS (WAVES * 64)   // 512
#define CHUNK 8                // T / THREADS elements per lane
#define MIN_GAP 5
#define MIN_SIZE 5
#define NEG (-3.402823466e38f)

// One block per batch (8 blocks -> 8 CUs, round-robin across XCDs).
// Thread t owns x[t*8 .. t*8+7] in registers.
// Suffix-max of b = 8-deep in-lane chain + 6-step wave Kogge-Stone (shfl)
// + 8-entry cross-wave LDS combine. Per-batch result -> d_ws; a 1-thread
// combine kernel sums in fixed order (bit-identical to the previous
// single-block version: fmax is exactly associative, sum order unchanged).
__global__ __launch_bounds__(THREADS, 2)
void custom_loss_batch(const float* __restrict__ w_phi,
                       const float* __restrict__ y,
                       const int* __restrict__ eps_p,
                       float* __restrict__ partial) {
    const int bat  = blockIdx.x;
    const int t    = threadIdx.x;
    const int wave = t >> 6;
    const int lane = t & 63;

    const float eps = (float)eps_p[0];
    const float y0  = y[bat * 2 + 0];
    const float y1  = y[bat * 2 + 1];
    const float* __restrict__ x = w_phi + (size_t)bat * T + (size_t)t * CHUNK;

    __shared__ float wmax[WAVES];             // per-wave max of b
    __shared__ float nxt0[WAVES][MIN_SIZE];   // full sm of first 5 elems of each wave
    __shared__ float wbest[WAVES];

    // ---- load 8 contiguous floats (2x float4) ----
    float xr[CHUNK];
    {
        float4 v0 = ((const float4*)x)[0];
        float4 v1 = ((const float4*)x)[1];
        xr[0] = v0.x; xr[1] = v0.y; xr[2] = v0.z; xr[3] = v0.w;
        xr[4] = v1.x; xr[5] = v1.y; xr[6] = v1.z; xr[7] = v1.w;
    }

    const float base = (float)(t * CHUNK);

    // ---- in-lane suffix max of b over the 8-chunk ----
    float ls[CHUNK];
    {
        float run = NEG;
        #pragma unroll
        for (int j = CHUNK - 1; j >= 0; j--) {
            float fj = base + (float)j;
            float bj = xr[j] + 0.5f * fmaxf(0.0f, fabsf(y1 - fj) - eps);
            run = fmaxf(run, bj);
            ls[j] = run;
        }
    }

    // ---- cross-lane inclusive suffix max within wave (Kogge-Stone) ----
    float inc = ls[0];
    #pragma unroll
    for (int off = 1; off < 64; off <<= 1) {
        float u = __shfl_down(inc, off, 64);
        inc = (lane + off < 64) ? fmaxf(inc, u) : inc;
    }
    // exclusive within wave: max over lanes > lane
    float S = __shfl_down(inc, 1, 64);
    if (lane == 63) S = NEG;

    // wave max (inclusive at lane 0) -> LDS
    if (lane == 0) wmax[wave] = inc;
    __syncthreads();

    // ---- suffix max over waves > wave ----
    float W = NEG;
    #pragma unroll
    for (int w2 = 0; w2 < WAVES; w2++) {
        if (w2 > wave) W = fmaxf(W, wmax[w2]);
    }
    const float SW = fmaxf(S, W);   // max of b over all elements past this lane's chunk

    // publish full sm of each wave's first 5 elements (for prev wave's lane 63)
    if (lane == 0) {
        #pragma unroll
        for (int k = 0; k < MIN_SIZE; k++)
            nxt0[wave][k] = fmaxf(ls[k], SW);
    }

    // neighbor-lane full sm for our last 5 elements (same wave via shfl)
    float nsm[MIN_SIZE];
    #pragma unroll
    for (int k = 0; k < MIN_SIZE; k++) {
        nsm[k] = __shfl_down(fmaxf(ls[k], SW), 1, 64);
    }
    __syncthreads();
    if (lane == 63 && wave < WAVES - 1) {
        #pragma unroll
        for (int k = 0; k < MIN_SIZE; k++) nsm[k] = nxt0[wave + 1][k];
    }

    // ---- best = max over valid i of a[i] + sm[i+MIN_SIZE] ----
    float best = NEG;
    const bool lastLane = (wave == WAVES - 1) && (lane == 63);
    #pragma unroll
    for (int j = 0; j < CHUNK; j++) {
        float fj = base + (float)j;
        float aj = xr[j] + 0.5f * fmaxf(0.0f, fabsf(y0 - fj) - eps);
        float smv;
        bool valid = true;
        if (j <= CHUNK - 1 - MIN_SIZE) {       // i+5 stays in this lane's chunk
            smv = fmaxf(ls[j + MIN_SIZE], SW);
        } else {                               // i+5 in next lane's chunk
            smv   = nsm[j - (CHUNK - MIN_SIZE)];
            valid = !lastLane;                 // i > T-1-MIN_SIZE at the very end
        }
        if (t == 0 && j < MIN_GAP) valid = false;   // i >= MIN_GAP
        if (valid) best = fmaxf(best, aj + smv);
    }

    // ---- wave reduce, then cross-wave reduce ----
    #pragma unroll
    for (int off = 32; off > 0; off >>= 1) {
        best = fmaxf(best, __shfl_down(best, off, 64));
    }
    if (lane == 0) wbest[wave] = best;
    __syncthreads();

    if (t == 0) {
        float r = wbest[0];
        #pragma unroll
        for (int w2 = 1; w2 < WAVES; w2++) r = fmaxf(r, wbest[w2]);
        // init = a[1] + b[1+MIN_SIZE]; both indices in thread 0's chunk
        float a1 = xr[1] + 0.5f * fmaxf(0.0f, fabsf(y0 - 1.0f) - eps);
        float b6 = xr[6] + 0.5f * fmaxf(0.0f, fabsf(y1 - (float)(1 + MIN_SIZE)) - eps);
        partial[bat] = fmaxf(r, a1 + b6);
    }
}

// Fixed-order sum of the 8 per-batch partials -> bit-identical mean.
__global__ void custom_loss_combine(const float* __restrict__ partial,
                                    float* __restrict__ out) {
    if (threadIdx.x == 0) {
        float s = 0.0f;
        #pragma unroll
        for (int k = 0; k < B; k++) s += partial[k];
        out[0] = s * 0.125f;
    }
}

extern "C" void kernel_launch(void* const* d_in, const int* in_sizes, int n_in,
                              void* d_out, int out_size, void* d_ws, size_t ws_size,
                              hipStream_t stream) {
    const float* w_phi = (const float*)d_in[0];   // (8,1,4096) fp32
    const float* y     = (const float*)d_in[1];   // (8,2) fp32
    const int*   eps   = (const int*)d_in[2];     // scalar int
    float* out     = (float*)d_out;               // scalar fp32
    float* partial = (float*)d_ws;                // 8 floats of workspace

    custom_loss_batch<<<B, THREADS, 0, stream>>>(w_phi, y, eps, partial);
    custom_loss_combine<<<1, 64, 0, stream>>>(partial, out);
}